// Round 2
// baseline (1721.175 us; speedup 1.0000x reference)
//
#include <hip/hip_runtime.h>
#include <hip/hip_bf16.h>

#define HSIZE 4096          // d-histogram buckets (r never exceeds ~1920 for any sane shape)
#define BIGD  0x3FFFFFFF

// ---------------- zero the workspace histogram ----------------
__global__ void zero_ws(int* hist, int* bs) {
    int i = blockIdx.x * 256 + threadIdx.x;
    if (i < HSIZE) hist[i] = 0;
    if (i == 0) bs[0] = 0;
}

// ---------------- per-point suppression distance ----------------
// pass 1: p_i = max score at i's pixel, rep_i = (no j<i at same pixel)
// pass 2: d_i = min Chebyshev distance to any point j with s_j > p_i
// hist[min(d,HSIZE-1)] += 1 for representatives (pixel-dedup'd count)
__global__ void compute_d(const int* __restrict__ kp, const float* __restrict__ sc,
                          int n, int* __restrict__ dout, int* __restrict__ hist) {
    int i = blockIdx.x * blockDim.x + threadIdx.x;
    if (i >= n) return;
    const int4* kp4 = (const int4*)kp;
    int4 ki = kp4[i];
    int yi = ki.z, xi = ki.w;
    float si = sc[i];

    // pass 1: pixel max + representative flag
    float p = si;
    int rep = 1;
    for (int j = 0; j < n; ++j) {
        int4 kj = kp4[j];                   // wave-uniform address -> L1 broadcast
        if (kj.z == yi && kj.w == xi) {
            float s = sc[j];
            if (s > p) p = s;
            if (j < i) rep = 0;
        }
    }

    // pass 2: min Chebyshev distance to strictly-higher-scored point
    int d = BIGD;
    for (int j = 0; j < n; ++j) {
        float s = sc[j];
        if (s > p) {
            int4 kj = kp4[j];
            int dy = yi - kj.z; if (dy < 0) dy = -dy;
            int dx = xi - kj.w; if (dx < 0) dx = -dx;
            int c = dy > dx ? dy : dx;
            if (c < d) d = c;
        }
    }
    dout[i] = d;
    if (rep) {
        int b = d < (HSIZE - 1) ? d : (HSIZE - 1);
        atomicAdd(&hist[b], 1);
    }
}

// ---------------- replicate the host binary search exactly ----------------
// F(r) = #kept pixels at radius r = suffix_sum(hist, r+1)
__global__ void bsearch_kernel(const int* __restrict__ hist,
                               const int* __restrict__ nret_, const int* __restrict__ rows_,
                               const int* __restrict__ cols_, int n, int* __restrict__ bs) {
    __shared__ int suf[HSIZE + 1];
    __shared__ int segtot[256];
    int t = threadIdx.x;

    // per-thread segment (16 buckets) suffix sums
    int seg = t * 16;
    int run = 0;
    for (int v = seg + 15; v >= seg; --v) {
        run += hist[v];
        suf[v] = run;
    }
    segtot[t] = run;
    __syncthreads();
    // inclusive suffix scan of segment totals: segtot[t] = sum_{u>=t}
    for (int s = 1; s < 256; s <<= 1) {
        int v = (t + s < 256) ? segtot[t + s] : 0;
        __syncthreads();
        segtot[t] += v;
        __syncthreads();
    }
    int after = (t < 255) ? segtot[t + 1] : 0;
    for (int v = seg; v < seg + 16; ++v) suf[v] += after;
    if (t == 0) suf[HSIZE] = 0;
    __syncthreads();

    if (t == 0) {
        int nret = nret_[0];
        int rows = rows_[0];
        int cols = cols_[0];
        // k_min/k_max: int(round(nret*(1∓0.1))) with double arithmetic like Python
        int kmin = (int)llround((double)nret * (1.0 - 0.1));
        int kmax = (int)llround((double)nret * (1.0 + 0.1));
        int mx = rows > cols ? rows : cols;
        int nr1 = nret > 1 ? nret : 1;
        int dvs = (int)sqrt((double)n / (double)nr1);   // int() truncation
        if (dvs < 1) dvs = 1;
        int high = mx / dvs;                             // floor div of positive ints
        if (high < 1) high = 1;
        int low = 1, prev_k = -1, r_final = -1;
        bool found = false;
        while (true) {
            int k = (low + high) / 2;
            if (k == prev_k || low > high) break;
            int r = k / 2;                               // == k_odd // 2 for both parities
            int cnt = (r + 1 <= HSIZE) ? suf[r + 1] : 0;
            if (cnt >= kmin && cnt <= kmax) { r_final = r; found = true; break; }
            else if (cnt < kmin) high = k - 1;
            else low = k + 1;
            prev_k = k;
        }
        if (!found) {
            int kfb = prev_k > 0 ? prev_k : 1;
            r_final = kfb / 2;
        }
        bs[0] = r_final;
    }
}

// ---------------- ordered selection + gather (single block) ----------------
// sel = kept indices ascending; if m < nret append non-kept ascending; truncate at nret.
// OUTPUT IS FLOAT32 (d_out is an f32 buffer; harness compares in bf16 space).
__global__ void select_write(const int* __restrict__ kp, const float* __restrict__ sc,
                             const int* __restrict__ d, const int* __restrict__ bs,
                             const int* __restrict__ nret_, int n,
                             float* __restrict__ out) {
    __shared__ int lds[256];
    __shared__ int mm;
    int t = threadIdx.x;
    int r = bs[0];
    int nret = nret_[0];

    // total kept points m
    int c = 0;
    for (int i = t; i < n; i += 256) c += (d[i] > r) ? 1 : 0;
    lds[t] = c;
    __syncthreads();
    for (int s = 128; s > 0; s >>= 1) {
        if (t < s) lds[t] += lds[t + s];
        __syncthreads();
    }
    if (t == 0) mm = lds[0];
    __syncthreads();
    int m = mm;

    int runK = 0, runN = 0;
    for (int base = 0; base < n; base += 256) {
        int i = base + t;
        int valid = (i < n) ? 1 : 0;
        int f  = (valid && d[i] > r) ? 1 : 0;
        int nf = (valid && !f) ? 1 : 0;
        int packed = f | (nf << 16);
        __syncthreads();                 // protect lds from previous chunk's readers
        lds[t] = packed;
        __syncthreads();
        // Hillis-Steele inclusive scan over 256 entries
        for (int s = 1; s < 256; s <<= 1) {
            int v = (t >= s) ? lds[t - s] : 0;
            __syncthreads();
            lds[t] += v;
            __syncthreads();
        }
        int inc = lds[t];
        int tot = lds[255];
        int exK = runK + (inc & 0xFFFF) - f;
        int exN = runN + (inc >> 16) - nf;
        if (valid) {
            int slot = -1;
            if (f) {
                if (exK < nret) slot = exK;                       // truncate kept at nret
            } else if (m < nret && (m + exN) < nret) {
                slot = m + exN;                                   // pad with non-kept
            }
            if (slot >= 0) {
                out[slot * 4 + 0] = (float)kp[i * 4 + 0];
                out[slot * 4 + 1] = (float)kp[i * 4 + 1];
                out[slot * 4 + 2] = (float)kp[i * 4 + 2];
                out[slot * 4 + 3] = (float)kp[i * 4 + 3];
                out[nret * 4 + slot] = sc[i];
            }
        }
        runK += tot & 0xFFFF;
        runN += tot >> 16;
    }
}

extern "C" void kernel_launch(void* const* d_in, const int* in_sizes, int n_in,
                              void* d_out, int out_size, void* d_ws, size_t ws_size,
                              hipStream_t stream) {
    const int*   kp   = (const int*)d_in[0];
    const float* sc   = (const float*)d_in[1];
    const int*   nret = (const int*)d_in[2];
    const int*   rows = (const int*)d_in[3];
    const int*   cols = (const int*)d_in[4];
    int n = in_sizes[1];                       // number of points (scores length)

    int* hist = (int*)d_ws;                    // HSIZE ints
    int* bs   = hist + HSIZE;                  // 1 int (chosen radius)
    int* dd   = bs + 16;                       // n ints (suppression distance)
    float* out = (float*)d_out;

    zero_ws<<<(HSIZE + 255) / 256, 256, 0, stream>>>(hist, bs);
    compute_d<<<(n + 255) / 256, 256, 0, stream>>>(kp, sc, n, dd, hist);
    bsearch_kernel<<<1, 256, 0, stream>>>(hist, nret, rows, cols, n, bs);
    select_write<<<1, 256, 0, stream>>>(kp, sc, dd, bs, nret, n, out);
}

// Round 3
// 110.679 us; speedup vs baseline: 15.5510x; 15.5510x over previous
//
#include <hip/hip_runtime.h>
#include <hip/hip_bf16.h>
#include <limits.h>

#define HSIZE 4096          // d-histogram buckets
#define BIGD  0x3FFFFFFF
#define HASHN 32768         // pixel hash table (power of 2), load factor ~0.3
#define HMASK (HASHN - 1)
#define JCH   512           // j-chunk staged in LDS per block

__device__ __forceinline__ unsigned hashf(int key) {
    return ((unsigned)key * 2654435761u >> 16) & HMASK;
}

// ---------------- init all workspace state (deterministic every call) ----------------
__global__ void init_ws(int* hist, int* bs, int* dd, int n,
                        int* hkey, int* hsb, int* hmi) {
    int i = blockIdx.x * 256 + threadIdx.x;
    if (i < HSIZE) hist[i] = 0;
    if (i == 0) bs[0] = 0;
    if (i < n) dd[i] = BIGD;
    if (i < HASHN) { hkey[i] = -1; hsb[i] = 0; hmi[i] = INT_MAX; }
}

// ---------------- hash insert: per-pixel max score + min point index ----------------
__global__ void hash_insert(const int* __restrict__ kp, const float* __restrict__ sc,
                            const int* __restrict__ cols_, int n,
                            int* __restrict__ hkey, int* __restrict__ hsb, int* __restrict__ hmi) {
    int i = blockIdx.x * 256 + threadIdx.x;
    if (i >= n) return;
    int cols = cols_[0];
    int key = kp[i * 4 + 2] * cols + kp[i * 4 + 3];
    unsigned slot = hashf(key);
    while (true) {
        int old = atomicCAS(&hkey[slot], -1, key);
        if (old == -1 || old == key) break;
        slot = (slot + 1) & HMASK;
    }
    atomicMax(&hsb[slot], __float_as_int(sc[i]));   // scores > 0: int-bit order == float order
    atomicMin(&hmi[slot], i);
}

// ---------------- per-point pixel-max p_i and representative flag ----------------
__global__ void prep(const int* __restrict__ kp,
                     const int* __restrict__ hkey, const int* __restrict__ hsb,
                     const int* __restrict__ hmi, const int* __restrict__ cols_, int n,
                     float* __restrict__ pmax, int* __restrict__ rep) {
    int i = blockIdx.x * 256 + threadIdx.x;
    if (i >= n) return;
    int cols = cols_[0];
    int key = kp[i * 4 + 2] * cols + kp[i * 4 + 3];
    unsigned slot = hashf(key);
    while (hkey[slot] != key) slot = (slot + 1) & HMASK;   // guaranteed present
    pmax[i] = __int_as_float(hsb[slot]);
    rep[i] = (hmi[slot] == i) ? 1 : 0;
}

// ---------------- d_i = min Chebyshev distance to any point with s_j > p_i ----------------
// grid: (ceil(n/256) i-blocks, ceil(n/JCH) j-chunks); combine via atomicMin.
__global__ void mindist(const int* __restrict__ kp, const float* __restrict__ sc,
                        const float* __restrict__ pmax, int n, int* __restrict__ dout) {
    __shared__ int   ly[JCH];
    __shared__ int   lx[JCH];
    __shared__ float ls[JCH];
    int t = threadIdx.x;
    int jbase = blockIdx.y * JCH;
    for (int u = t; u < JCH; u += 256) {
        int j = jbase + u;
        if (j < n) {
            ly[u] = kp[j * 4 + 2];
            lx[u] = kp[j * 4 + 3];
            ls[u] = sc[j];
        } else {
            ly[u] = 0; lx[u] = 0; ls[u] = -1e30f;   // never qualifies
        }
    }
    __syncthreads();
    int i = blockIdx.x * 256 + t;
    if (i >= n) return;
    int yi = kp[i * 4 + 2], xi = kp[i * 4 + 3];
    float p = pmax[i];
    int d = BIGD;
    #pragma unroll 8
    for (int u = 0; u < JCH; ++u) {
        float s = ls[u];                       // uniform address -> LDS broadcast
        int dy = yi - ly[u]; dy = dy < 0 ? -dy : dy;
        int dx = xi - lx[u]; dx = dx < 0 ? -dx : dx;
        int c = dy > dx ? dy : dx;
        bool q = (s > p) & (c < d);
        d = q ? c : d;
    }
    if (d < BIGD) atomicMin(&dout[i], d);
}

// ---------------- histogram of d over representatives (pixel-dedup'd) ----------------
__global__ void hist_k(const int* __restrict__ dd, const int* __restrict__ rep,
                       int n, int* __restrict__ hist) {
    int i = blockIdx.x * 256 + threadIdx.x;
    if (i >= n) return;
    if (rep[i]) {
        int b = dd[i] < (HSIZE - 1) ? dd[i] : (HSIZE - 1);
        atomicAdd(&hist[b], 1);
    }
}

// ---------------- replicate the host binary search exactly ----------------
// F(r) = #kept pixels at radius r = suffix_sum(hist, r+1)
__global__ void bsearch_kernel(const int* __restrict__ hist,
                               const int* __restrict__ nret_, const int* __restrict__ rows_,
                               const int* __restrict__ cols_, int n, int* __restrict__ bs) {
    __shared__ int suf[HSIZE + 1];
    __shared__ int segtot[256];
    int t = threadIdx.x;

    int seg = t * 16;
    int run = 0;
    for (int v = seg + 15; v >= seg; --v) {
        run += hist[v];
        suf[v] = run;
    }
    segtot[t] = run;
    __syncthreads();
    for (int s = 1; s < 256; s <<= 1) {
        int v = (t + s < 256) ? segtot[t + s] : 0;
        __syncthreads();
        segtot[t] += v;
        __syncthreads();
    }
    int after = (t < 255) ? segtot[t + 1] : 0;
    for (int v = seg; v < seg + 16; ++v) suf[v] += after;
    if (t == 0) suf[HSIZE] = 0;
    __syncthreads();

    if (t == 0) {
        int nret = nret_[0];
        int rows = rows_[0];
        int cols = cols_[0];
        int kmin = (int)llround((double)nret * (1.0 - 0.1));
        int kmax = (int)llround((double)nret * (1.0 + 0.1));
        int mx = rows > cols ? rows : cols;
        int nr1 = nret > 1 ? nret : 1;
        int dvs = (int)sqrt((double)n / (double)nr1);   // int() truncation
        if (dvs < 1) dvs = 1;
        int high = mx / dvs;
        if (high < 1) high = 1;
        int low = 1, prev_k = -1, r_final = -1;
        bool found = false;
        while (true) {
            int k = (low + high) / 2;
            if (k == prev_k || low > high) break;
            int r = k / 2;                               // == k_odd // 2 for both parities
            int cnt = (r + 1 <= HSIZE) ? suf[r + 1] : 0;
            if (cnt >= kmin && cnt <= kmax) { r_final = r; found = true; break; }
            else if (cnt < kmin) high = k - 1;
            else low = k + 1;
            prev_k = k;
        }
        if (!found) {
            int kfb = prev_k > 0 ? prev_k : 1;
            r_final = kfb / 2;
        }
        bs[0] = r_final;
    }
}

// ---------------- ordered selection + gather (single block, ballot scans) ----------------
// sel = kept indices ascending; if m < nret append non-kept ascending; truncate at nret.
// OUTPUT IS FLOAT32 (d_out is an f32 buffer; harness compares in bf16 space).
__global__ void select_write(const int* __restrict__ kp, const float* __restrict__ sc,
                             const int* __restrict__ d, const int* __restrict__ bs,
                             const int* __restrict__ nret_, int n,
                             float* __restrict__ out) {
    __shared__ int wtotK[4], wtotN[4];
    __shared__ int red[256];
    int t = threadIdx.x;
    int lane = t & 63;
    int w = t >> 6;
    int r = bs[0];
    int nret = nret_[0];

    // total kept points m
    int c = 0;
    for (int i = t; i < n; i += 256) c += (d[i] > r) ? 1 : 0;
    red[t] = c;
    __syncthreads();
    for (int s = 128; s > 0; s >>= 1) {
        if (t < s) red[t] += red[t + s];
        __syncthreads();
    }
    int m = red[0];
    __syncthreads();

    unsigned long long lanemask = (lane == 0) ? 0ull : (~0ull >> (64 - lane));
    int runK = 0, runN = 0;
    for (int base = 0; base < n; base += 256) {
        int i = base + t;
        bool valid = i < n;
        bool f  = valid && (d[i] > r);
        bool nf = valid && !f;
        unsigned long long mk = __ballot(f);
        unsigned long long mn = __ballot(nf);
        int pk = __popcll(mk & lanemask);
        int pn = __popcll(mn & lanemask);
        if (lane == 0) { wtotK[w] = __popcll(mk); wtotN[w] = __popcll(mn); }
        __syncthreads();
        int exK = runK + pk;
        int exN = runN + pn;
        for (int u = 0; u < w; ++u) { exK += wtotK[u]; exN += wtotN[u]; }
        int ctK = wtotK[0] + wtotK[1] + wtotK[2] + wtotK[3];
        int ctN = wtotN[0] + wtotN[1] + wtotN[2] + wtotN[3];
        __syncthreads();
        if (valid) {
            int slot = -1;
            if (f) {
                if (exK < nret) slot = exK;                    // truncate kept at nret
            } else if (nf && m < nret && (m + exN) < nret) {
                slot = m + exN;                                // pad with non-kept
            }
            if (slot >= 0) {
                out[slot * 4 + 0] = (float)kp[i * 4 + 0];
                out[slot * 4 + 1] = (float)kp[i * 4 + 1];
                out[slot * 4 + 2] = (float)kp[i * 4 + 2];
                out[slot * 4 + 3] = (float)kp[i * 4 + 3];
                out[nret * 4 + slot] = sc[i];
            }
        }
        runK += ctK;
        runN += ctN;
    }
}

extern "C" void kernel_launch(void* const* d_in, const int* in_sizes, int n_in,
                              void* d_out, int out_size, void* d_ws, size_t ws_size,
                              hipStream_t stream) {
    const int*   kp   = (const int*)d_in[0];
    const float* sc   = (const float*)d_in[1];
    const int*   nret = (const int*)d_in[2];
    const int*   rows = (const int*)d_in[3];
    const int*   cols = (const int*)d_in[4];
    int n = in_sizes[1];                       // number of points

    int* hist = (int*)d_ws;                    // HSIZE
    int* bs   = hist + HSIZE;                  // 16
    int* dd   = bs + 16;                       // n
    float* pmax = (float*)(dd + n);            // n
    int* rep  = (int*)(pmax + n);              // n
    int* hkey = rep + n;                       // HASHN
    int* hsb  = hkey + HASHN;                  // HASHN
    int* hmi  = hsb + HASHN;                   // HASHN
    float* out = (float*)d_out;

    int nb = (n + 255) / 256;
    int initN = HASHN > HSIZE ? HASHN : HSIZE;
    if (n > initN) initN = n;

    init_ws<<<(initN + 255) / 256, 256, 0, stream>>>(hist, bs, dd, n, hkey, hsb, hmi);
    hash_insert<<<nb, 256, 0, stream>>>(kp, sc, cols, n, hkey, hsb, hmi);
    prep<<<nb, 256, 0, stream>>>(kp, hkey, hsb, hmi, cols, n, pmax, rep);
    dim3 grid(nb, (n + JCH - 1) / JCH);
    mindist<<<grid, 256, 0, stream>>>(kp, sc, pmax, n, dd);
    hist_k<<<nb, 256, 0, stream>>>(dd, rep, n, hist);
    bsearch_kernel<<<1, 256, 0, stream>>>(hist, nret, rows, cols, n, bs);
    select_write<<<1, 256, 0, stream>>>(kp, sc, dd, bs, nret, n, out);
}